// Round 1
// baseline (161.947 us; speedup 1.0000x reference)
//
#include <hip/hip_runtime.h>

typedef __bf16 bf16_t;
typedef __attribute__((ext_vector_type(8))) __bf16 bf16x8;
typedef __attribute__((ext_vector_type(4))) __bf16 bf16x4;
typedef __attribute__((ext_vector_type(4))) float f32x4;

#define S_LEN 4096
#define D_MODEL 1024
#define NH 16
#define DKH 64
#define WIN 256
#define NGLOB 16
#define HSZ (S_LEN * DKH)  // 262144 elems per head per tensor

// async 16B global->LDS copy (dest: wave-uniform base + lane*16)
__device__ inline void g2l16(const void* g, void* l) {
  __builtin_amdgcn_global_load_lds(
      (__attribute__((address_space(1))) void*)(void*)g,
      (__attribute__((address_space(3))) void*)l, 16, 0, 0);
}

// ---------------------------------------------------------------------------
// C[MxN] = A[M,K] * B[K,N] (+bias), A row-major bf16, Bt = B^T [N,K] bf16.
// 128x128 tile, BK=32, 4 waves (2x2), each wave 64x64 via 4x4 of 16x16x32 MFMA.
// MODE 0: write Q bf16 [h][s][64], value scaled by 0.125 (1/sqrt(DK))
// MODE 1: write K bf16 [h][s][64]
// MODE 2: write V^T bf16 [h][64][s]
// MODE 3: write f32 row-major [M,N] (+bias) -> final output
// ---------------------------------------------------------------------------
template <int MODE>
__global__ __launch_bounds__(256) void gemm128(const bf16_t* __restrict__ A,
                                               const bf16_t* __restrict__ Bt,
                                               const float* __restrict__ bias,
                                               void* __restrict__ Cout) {
  __shared__ bf16_t As[128 * 32];
  __shared__ bf16_t Bs[128 * 32];
  const int tid = threadIdx.x;
  const int wave = tid >> 6, lane = tid & 63;
  const int m0 = blockIdx.y * 128, n0 = blockIdx.x * 128;
  const int wr = wave >> 1, wc = wave & 1;

  f32x4 acc[4][4];
#pragma unroll
  for (int i = 0; i < 4; i++)
#pragma unroll
    for (int j = 0; j < 4; j++) acc[i][j] = {0.f, 0.f, 0.f, 0.f};

  const int srow = lane >> 2;        // staging: row within 16-row chunk
  const int scol = (lane & 3) * 8;   // staging: col (8 bf16 = 16B)
  const int fr = lane & 15;          // fragment row/col
  const int fk = (lane >> 4) * 8;    // fragment k offset

  for (int k0 = 0; k0 < D_MODEL; k0 += 32) {
#pragma unroll
    for (int i = 0; i < 2; i++) {
      const int c = wave * 2 + i;  // chunk 0..7 (1KB each)
      const int row = c * 16 + srow;
      g2l16(A + (size_t)(m0 + row) * D_MODEL + k0 + scol, &As[c * 512]);
      g2l16(Bt + (size_t)(n0 + row) * D_MODEL + k0 + scol, &Bs[c * 512]);
    }
    __syncthreads();
    bf16x8 af[4], bfr[4];
#pragma unroll
    for (int m = 0; m < 4; m++)
      af[m] = *(const bf16x8*)&As[(wr * 64 + m * 16 + fr) * 32 + fk];
#pragma unroll
    for (int n = 0; n < 4; n++)
      bfr[n] = *(const bf16x8*)&Bs[(wc * 64 + n * 16 + fr) * 32 + fk];
#pragma unroll
    for (int m = 0; m < 4; m++)
#pragma unroll
      for (int n = 0; n < 4; n++)
        acc[m][n] = __builtin_amdgcn_mfma_f32_16x16x32_bf16(af[m], bfr[n],
                                                            acc[m][n], 0, 0, 0);
    __syncthreads();
  }

  // epilogue: C[row=(lane>>4)*4+r][col=lane&15] per 16x16 frag
  const int cr = (lane >> 4) * 4;
  const int cc = lane & 15;
#pragma unroll
  for (int m = 0; m < 4; m++) {
    const int rowg = m0 + wr * 64 + m * 16 + cr;
#pragma unroll
    for (int n = 0; n < 4; n++) {
      const int colg = n0 + wc * 64 + n * 16 + cc;
      const float bv = bias[colg];
#pragma unroll
      for (int r = 0; r < 4; r++) {
        const int s = rowg + r;
        const float v = acc[m][n][r] + bv;
        if (MODE == 3) {
          ((float*)Cout)[(size_t)s * D_MODEL + colg] = v;
        } else {
          const int h = colg >> 6, d = colg & 63;
          bf16_t* out = (bf16_t*)Cout;
          if (MODE == 0)
            out[h * HSZ + s * DKH + d] = (bf16_t)(v * 0.125f);
          else if (MODE == 1)
            out[h * HSZ + s * DKH + d] = (bf16_t)v;
          else
            out[h * HSZ + d * S_LEN + s] = (bf16_t)v;
        }
      }
    }
  }
}

// f32 -> bf16 elementwise (4 per thread)
__global__ void convx(const float* __restrict__ in, bf16_t* __restrict__ out) {
  const int i = (blockIdx.x * 256 + threadIdx.x) * 4;
  const float4 v = *(const float4*)&in[i];
  bf16x4 o = {(bf16_t)v.x, (bf16_t)v.y, (bf16_t)v.z, (bf16_t)v.w};
  *(bf16x4*)&out[i] = o;
}

// transpose+convert 4 weight matrices [K,N] f32 -> [N,K] bf16
__global__ void convw(const float* __restrict__ W0, const float* __restrict__ W1,
                      const float* __restrict__ W2, const float* __restrict__ W3,
                      bf16_t* __restrict__ out) {
  __shared__ float t[64][65];
  const float* W = blockIdx.z == 0 ? W0 : blockIdx.z == 1 ? W1
                  : blockIdx.z == 2 ? W2 : W3;
  bf16_t* Wt = out + (size_t)blockIdx.z * (D_MODEL * D_MODEL);
  const int k0 = blockIdx.y * 64, n0 = blockIdx.x * 64;
  const int tx = threadIdx.x & 63, ty = threadIdx.x >> 6;
#pragma unroll
  for (int i = 0; i < 16; i++) {
    const int r = i * 4 + ty;
    t[r][tx] = W[(size_t)(k0 + r) * D_MODEL + n0 + tx];
  }
  __syncthreads();
#pragma unroll
  for (int i = 0; i < 16; i++) {
    const int r = i * 4 + ty;
    Wt[(size_t)(n0 + r) * D_MODEL + k0 + tx] = (bf16_t)t[tx][r];
  }
}

// ---------------------------------------------------------------------------
// Sparse flash attention. 1 wave = 16 q-rows of one head; block = 4 waves = 64
// rows. Key tiles of 32: {tile 0 if separated} U [ (q0-256)>>5 .. (q0+15)>>5 ].
// Q pre-scaled by 1/8. Online softmax with per-row running (m, l).
// ---------------------------------------------------------------------------
__global__ __launch_bounds__(256) void attn_kern(const bf16_t* __restrict__ Q,
                                                 const bf16_t* __restrict__ K,
                                                 const bf16_t* __restrict__ V,
                                                 bf16_t* __restrict__ O) {
  __shared__ bf16_t p_lds[4][16 * 32];
  const int wave = threadIdx.x >> 6, lane = threadIdx.x & 63;
  const int h = blockIdx.y;
  const int q0 = blockIdx.x * 64 + wave * 16;
  const bf16_t* Qh = Q + h * HSZ;
  const bf16_t* Kh = K + h * HSZ;
  const bf16_t* Vh = V + h * HSZ;  // V^T: [64][S]

  const int fr = lane & 15;
  const int fk = (lane >> 4) * 8;
  const int cr = (lane >> 4) * 4;

  const bf16x8 aq0 = *(const bf16x8*)&Qh[(q0 + fr) * DKH + fk];
  const bf16x8 aq1 = *(const bf16x8*)&Qh[(q0 + fr) * DKH + 32 + fk];

  f32x4 acc_o[4];
#pragma unroll
  for (int i = 0; i < 4; i++) acc_o[i] = {0.f, 0.f, 0.f, 0.f};
  float mrow[4] = {-1e30f, -1e30f, -1e30f, -1e30f};
  float lrow[4] = {0.f, 0.f, 0.f, 0.f};

  const int kt_end = (q0 + 15) >> 5;
  int kt_lo = (q0 - WIN) >> 5;
  if (kt_lo < 0) kt_lo = 0;
  const int nt = kt_end - kt_lo + 1 + (kt_lo > 0 ? 1 : 0);

  for (int t = 0; t < nt; t++) {
    const int kt = (kt_lo > 0) ? (t == 0 ? 0 : kt_lo + t - 1) : t;
    const int kb = kt * 32;

    const bf16x8 bk00 = *(const bf16x8*)&Kh[(kb + fr) * DKH + fk];
    const bf16x8 bk01 = *(const bf16x8*)&Kh[(kb + fr) * DKH + 32 + fk];
    const bf16x8 bk10 = *(const bf16x8*)&Kh[(kb + 16 + fr) * DKH + fk];
    const bf16x8 bk11 = *(const bf16x8*)&Kh[(kb + 16 + fr) * DKH + 32 + fk];

    f32x4 s0 = {0.f, 0.f, 0.f, 0.f}, s1 = {0.f, 0.f, 0.f, 0.f};
    s0 = __builtin_amdgcn_mfma_f32_16x16x32_bf16(aq0, bk00, s0, 0, 0, 0);
    s0 = __builtin_amdgcn_mfma_f32_16x16x32_bf16(aq1, bk01, s0, 0, 0, 0);
    s1 = __builtin_amdgcn_mfma_f32_16x16x32_bf16(aq0, bk10, s1, 0, 0, 0);
    s1 = __builtin_amdgcn_mfma_f32_16x16x32_bf16(aq1, bk11, s1, 0, 0, 0);

    float alpha[4];
#pragma unroll
    for (int r = 0; r < 4; r++) {
      const int ig = q0 + cr + r;
      const int j0 = kb + fr, j1 = kb + 16 + fr;
      const float v0 =
          (j0 <= ig && (ig - j0 <= WIN || j0 < NGLOB)) ? s0[r] : -1e30f;
      const float v1 =
          (j1 <= ig && (ig - j1 <= WIN || j1 < NGLOB)) ? s1[r] : -1e30f;
      float mt = fmaxf(v0, v1);
      mt = fmaxf(mt, __shfl_xor(mt, 1));
      mt = fmaxf(mt, __shfl_xor(mt, 2));
      mt = fmaxf(mt, __shfl_xor(mt, 4));
      mt = fmaxf(mt, __shfl_xor(mt, 8));
      const float mn = fmaxf(mrow[r], mt);
      alpha[r] = __expf(mrow[r] - mn);
      mrow[r] = mn;
      const float p0 = __expf(v0 - mn);
      const float p1 = __expf(v1 - mn);
      float ps = p0 + p1;
      ps += __shfl_xor(ps, 1);
      ps += __shfl_xor(ps, 2);
      ps += __shfl_xor(ps, 4);
      ps += __shfl_xor(ps, 8);
      lrow[r] = lrow[r] * alpha[r] + ps;
      p_lds[wave][(cr + r) * 32 + fr] = (bf16_t)p0;
      p_lds[wave][(cr + r) * 32 + 16 + fr] = (bf16_t)p1;
    }

    const bf16x8 pa = *(const bf16x8*)&p_lds[wave][fr * 32 + fk];
#pragma unroll
    for (int fd = 0; fd < 4; fd++) {
#pragma unroll
      for (int r = 0; r < 4; r++) acc_o[fd][r] *= alpha[r];
      const bf16x8 bv =
          *(const bf16x8*)&Vh[(fd * 16 + fr) * S_LEN + kb + fk];
      acc_o[fd] = __builtin_amdgcn_mfma_f32_16x16x32_bf16(pa, bv, acc_o[fd], 0, 0, 0);
    }
  }

  float inv[4];
#pragma unroll
  for (int r = 0; r < 4; r++) inv[r] = 1.0f / lrow[r];
#pragma unroll
  for (int fd = 0; fd < 4; fd++)
#pragma unroll
    for (int r = 0; r < 4; r++) {
      const int s = q0 + cr + r;
      O[(size_t)s * D_MODEL + h * DKH + fd * 16 + fr] =
          (bf16_t)(acc_o[fd][r] * inv[r]);
    }
}

extern "C" void kernel_launch(void* const* d_in, const int* in_sizes, int n_in,
                              void* d_out, int out_size, void* d_ws,
                              size_t ws_size, hipStream_t stream) {
  const float* query = (const float*)d_in[0];
  const float* key = (const float*)d_in[1];
  const float* value = (const float*)d_in[2];
  const float* Wq = (const float*)d_in[3];
  const float* bq = (const float*)d_in[4];
  const float* Wk = (const float*)d_in[5];
  const float* bk = (const float*)d_in[6];
  const float* Wv = (const float*)d_in[7];
  const float* bv = (const float*)d_in[8];
  const float* Wo = (const float*)d_in[9];
  const float* bo = (const float*)d_in[10];

  char* ws = (char*)d_ws;
  bf16_t* Qb = (bf16_t*)(ws);                    // 8 MiB [16][4096][64]
  bf16_t* Kb = (bf16_t*)(ws + (8ull << 20));     // 8 MiB
  bf16_t* Vtb = (bf16_t*)(ws + (16ull << 20));   // 8 MiB [16][64][4096]
  bf16_t* Wt = (bf16_t*)(ws + (24ull << 20));    // 4 x 2 MiB (Wq^T..Wo^T)
  bf16_t* Xb = (bf16_t*)(ws + (32ull << 20));    // 8 MiB (reused)
  bf16_t* Ab = (bf16_t*)(ws + (40ull << 20));    // 8 MiB attn out [4096][1024]

  const size_t WSTRIDE = (size_t)D_MODEL * D_MODEL;

  convw<<<dim3(16, 16, 4), 256, 0, stream>>>(Wq, Wk, Wv, Wo, Wt);

  convx<<<4096, 256, 0, stream>>>(query, Xb);
  gemm128<0><<<dim3(8, 32), 256, 0, stream>>>(Xb, Wt + 0 * WSTRIDE, bq, Qb);
  convx<<<4096, 256, 0, stream>>>(key, Xb);
  gemm128<1><<<dim3(8, 32), 256, 0, stream>>>(Xb, Wt + 1 * WSTRIDE, bk, Kb);
  convx<<<4096, 256, 0, stream>>>(value, Xb);
  gemm128<2><<<dim3(8, 32), 256, 0, stream>>>(Xb, Wt + 2 * WSTRIDE, bv, Vtb);

  attn_kern<<<dim3(64, 16), 256, 0, stream>>>(Qb, Kb, Vtb, Ab);

  gemm128<3><<<dim3(8, 32), 256, 0, stream>>>(Ab, Wt + 3 * WSTRIDE, bo, d_out);
}

// Round 4
// 130.270 us; speedup vs baseline: 1.2432x; 1.2432x over previous
//
#include <hip/hip_runtime.h>

typedef __bf16 bf16_t;
typedef __attribute__((ext_vector_type(8))) __bf16 bf16x8;
typedef __attribute__((ext_vector_type(4))) __bf16 bf16x4;
typedef __attribute__((ext_vector_type(2))) __bf16 bf16x2;
typedef __attribute__((ext_vector_type(4))) float f32x4;

#define S_LEN 4096
#define D_MODEL 1024
#define NH 16
#define DKH 64
#define WIN 256
#define NGLOB 16
#define HSZ (S_LEN * DKH)

// async 16B global->LDS copy (dest: wave-uniform base + lane*16)
__device__ inline void g2l16(const void* g, void* l) {
  __builtin_amdgcn_global_load_lds(
      (__attribute__((address_space(1))) void*)(void*)g,
      (__attribute__((address_space(3))) void*)l, 16, 0, 0);
}

// ---------------------------------------------------------------------------
// Shared GEMM body: C[128x128] = A[128,K] * Bt[128,K]^T, bf16 in, f32 acc.
// 4 waves (2x2), each 64x64 via 4x4 of 16x16x32 MFMA, BK=32,
// global_load_lds width-16 staging.
// ---------------------------------------------------------------------------
#define GEMM_BODY(A, Bt)                                                      \
  __shared__ bf16_t As[128 * 32];                                             \
  __shared__ bf16_t Bs[128 * 32];                                             \
  const int tid = threadIdx.x;                                                \
  const int wave = tid >> 6, lane = tid & 63;                                 \
  const int wr = wave >> 1, wc = wave & 1;                                    \
  f32x4 acc[4][4];                                                            \
  _Pragma("unroll") for (int i = 0; i < 4; i++) _Pragma("unroll")             \
      for (int j = 0; j < 4; j++) acc[i][j] = {0.f, 0.f, 0.f, 0.f};          \
  const int srow = lane >> 2;                                                 \
  const int scol = (lane & 3) * 8;                                            \
  const int fr = lane & 15;                                                   \
  const int fk = (lane >> 4) * 8;                                             \
  for (int k0 = 0; k0 < D_MODEL; k0 += 32) {                                  \
    _Pragma("unroll") for (int i = 0; i < 2; i++) {                           \
      const int c = wave * 2 + i;                                             \
      const int row = c * 16 + srow;                                          \
      g2l16(A + (size_t)(m0 + row) * D_MODEL + k0 + scol, &As[c * 512]);      \
      g2l16(Bt + (size_t)(n0 + row) * D_MODEL + k0 + scol, &Bs[c * 512]);     \
    }                                                                         \
    __syncthreads();                                                          \
    bf16x8 af[4], bfr[4];                                                     \
    _Pragma("unroll") for (int m = 0; m < 4; m++) af[m] =                     \
        *(const bf16x8*)&As[(wr * 64 + m * 16 + fr) * 32 + fk];               \
    _Pragma("unroll") for (int n = 0; n < 4; n++) bfr[n] =                    \
        *(const bf16x8*)&Bs[(wc * 64 + n * 16 + fr) * 32 + fk];               \
    _Pragma("unroll") for (int m = 0; m < 4; m++) _Pragma("unroll")           \
        for (int n = 0; n < 4; n++) acc[m][n] =                               \
            __builtin_amdgcn_mfma_f32_16x16x32_bf16(af[m], bfr[n],            \
                                                    acc[m][n], 0, 0, 0);      \
    __syncthreads();                                                          \
  }                                                                           \
  const int cr = (lane >> 4) * 4;                                             \
  const int cc = lane & 15;

// ---------------------------------------------------------------------------
// Fused Q/K/V projection: blockIdx.z selects input/weight/bias/output.
// z=0: Q bf16 [h][s][64] scaled 0.125; z=1: K bf16 [h][s][64];
// z=2: V^T bf16 [h][64][s].
// ---------------------------------------------------------------------------
__global__ __launch_bounds__(256) void gemm_qkv(
    const bf16_t* __restrict__ Xq, const bf16_t* __restrict__ Xk,
    const bf16_t* __restrict__ Xv, const bf16_t* __restrict__ Wt,
    const float* __restrict__ bq, const float* __restrict__ bk,
    const float* __restrict__ bv, bf16_t* __restrict__ Qo,
    bf16_t* __restrict__ Ko, bf16_t* __restrict__ Vto) {
  const int which = blockIdx.z;
  const bf16_t* A = which == 0 ? Xq : which == 1 ? Xk : Xv;
  const bf16_t* Bt = Wt + (size_t)which * (D_MODEL * D_MODEL);
  const float* bias = which == 0 ? bq : which == 1 ? bk : bv;
  const int m0 = blockIdx.y * 128, n0 = blockIdx.x * 128;

  GEMM_BODY(A, Bt)

#pragma unroll
  for (int m = 0; m < 4; m++) {
    const int rowg = m0 + wr * 64 + m * 16 + cr;
#pragma unroll
    for (int n = 0; n < 4; n++) {
      const int colg = n0 + wc * 64 + n * 16 + cc;
      const float bv_ = bias[colg];
      const int h = colg >> 6, d = colg & 63;
#pragma unroll
      for (int r = 0; r < 4; r++) {
        const int s = rowg + r;
        const float v = acc[m][n][r] + bv_;
        if (which == 0)
          Qo[h * HSZ + s * DKH + d] = (bf16_t)(v * 0.125f);
        else if (which == 1)
          Ko[h * HSZ + s * DKH + d] = (bf16_t)v;
        else
          Vto[h * HSZ + d * S_LEN + s] = (bf16_t)v;
      }
    }
  }
}

// Final output projection: f32 out with bias.
__global__ __launch_bounds__(256) void gemm_out(const bf16_t* __restrict__ A_,
                                                const bf16_t* __restrict__ Bt_,
                                                const float* __restrict__ bias,
                                                float* __restrict__ Cout) {
  const int m0 = blockIdx.y * 128, n0 = blockIdx.x * 128;
  GEMM_BODY(A_, Bt_)
#pragma unroll
  for (int m = 0; m < 4; m++) {
    const int rowg = m0 + wr * 64 + m * 16 + cr;
#pragma unroll
    for (int n = 0; n < 4; n++) {
      const int colg = n0 + wc * 64 + n * 16 + cc;
      const float bv_ = bias[colg];
#pragma unroll
      for (int r = 0; r < 4; r++)
        Cout[(size_t)(rowg + r) * D_MODEL + colg] = acc[m][n][r] + bv_;
    }
  }
}

// f32 -> bf16 for the 3 inputs in one launch.
// NOTE: grid.x MUST be 4096 (4096*256*4 = S*D elements). R2/R3 used 1024 and
// converted only 1/4 of each input -> deterministic junk in rows 1024+.
__global__ void convx3(const float* __restrict__ q, const float* __restrict__ k,
                       const float* __restrict__ v, bf16_t* __restrict__ oq,
                       bf16_t* __restrict__ ok, bf16_t* __restrict__ ov) {
  const float* in = blockIdx.y == 0 ? q : blockIdx.y == 1 ? k : v;
  bf16_t* out = blockIdx.y == 0 ? oq : blockIdx.y == 1 ? ok : ov;
  const int i = (blockIdx.x * 256 + threadIdx.x) * 4;
  const float4 x = *(const float4*)&in[i];
  bf16x4 o = {(bf16_t)x.x, (bf16_t)x.y, (bf16_t)x.z, (bf16_t)x.w};
  *(bf16x4*)&out[i] = o;
}

// transpose+convert 4 weight matrices [K,N] f32 -> [N,K] bf16
__global__ void convw(const float* __restrict__ W0, const float* __restrict__ W1,
                      const float* __restrict__ W2, const float* __restrict__ W3,
                      bf16_t* __restrict__ out) {
  __shared__ float t[64][65];
  const float* W = blockIdx.z == 0 ? W0 : blockIdx.z == 1 ? W1
                  : blockIdx.z == 2 ? W2 : W3;
  bf16_t* Wt = out + (size_t)blockIdx.z * (D_MODEL * D_MODEL);
  const int k0 = blockIdx.y * 64, n0 = blockIdx.x * 64;
  const int tx = threadIdx.x & 63, ty = threadIdx.x >> 6;
#pragma unroll
  for (int i = 0; i < 16; i++) {
    const int r = i * 4 + ty;
    t[r][tx] = W[(size_t)(k0 + r) * D_MODEL + n0 + tx];
  }
  __syncthreads();
#pragma unroll
  for (int i = 0; i < 16; i++) {
    const int r = i * 4 + ty;
    Wt[(size_t)(n0 + r) * D_MODEL + k0 + tx] = (bf16_t)t[tx][r];
  }
}

// ---------------------------------------------------------------------------
// Sparse flash attention, swapped-QK^T form.
// 1 wave = 16 q-rows of one head. s = mfma(K_frag, Q_frag) -> C[row=k][col=q]:
// each lane owns ONE q (lane&15) with 8 k-values in regs -> softmax reduce is
// 2 shfl(max) + 2 shfl(sum); running (m,l) are per-lane scalars.
// P re-formed to PV A-fragment via padded per-wave LDS (stride 40 bf16).
// ---------------------------------------------------------------------------
__global__ __launch_bounds__(256) void attn_kern(const bf16_t* __restrict__ Q,
                                                 const bf16_t* __restrict__ K,
                                                 const bf16_t* __restrict__ V,
                                                 bf16_t* __restrict__ O) {
  __shared__ bf16_t p_lds[4][16 * 40];  // [wave][q*40 + k], padded
  const int wave = threadIdx.x >> 6, lane = threadIdx.x & 63;
  const int h = blockIdx.y;
  const int q0 = blockIdx.x * 64 + wave * 16;
  const bf16_t* Qh = Q + h * HSZ;
  const bf16_t* Kh = K + h * HSZ;
  const bf16_t* Vh = V + h * HSZ;  // V^T: [64][S]

  const int fr = lane & 15;
  const int fk = (lane >> 4) * 8;
  const int cr = (lane >> 4) * 4;

  // Q as MFMA B-operand (same register layout as A)
  const bf16x8 aq0 = *(const bf16x8*)&Qh[(q0 + fr) * DKH + fk];
  const bf16x8 aq1 = *(const bf16x8*)&Qh[(q0 + fr) * DKH + 32 + fk];

  f32x4 acc_o[4];
#pragma unroll
  for (int i = 0; i < 4; i++) acc_o[i] = {0.f, 0.f, 0.f, 0.f};
  float m_run = -1e30f, l_run = 0.f;

  const int kt_end = (q0 + 15) >> 5;
  int kt_lo = (q0 - WIN) >> 5;
  if (kt_lo < 0) kt_lo = 0;
  const int nt = kt_end - kt_lo + 1 + (kt_lo > 0 ? 1 : 0);

#define TILE_KB(t) ((kt_lo > 0) ? ((t) == 0 ? 0 : (kt_lo + (t)-1) * 32) : (t)*32)
#define LOADK(kb, A0, A1, A2, A3)                              \
  A0 = *(const bf16x8*)&Kh[((kb) + fr) * DKH + fk];            \
  A1 = *(const bf16x8*)&Kh[((kb) + fr) * DKH + 32 + fk];       \
  A2 = *(const bf16x8*)&Kh[((kb) + 16 + fr) * DKH + fk];       \
  A3 = *(const bf16x8*)&Kh[((kb) + 16 + fr) * DKH + 32 + fk];

  bf16x8 kc0, kc1, kc2, kc3;
  {
    const int kb0 = TILE_KB(0);
    LOADK(kb0, kc0, kc1, kc2, kc3)
  }

  const int iq = q0 + fr;
  bf16_t* prow = &p_lds[wave][fr * 40];
  const bf16x8* pread = (const bf16x8*)&p_lds[wave][fr * 40 + fk];

  for (int t = 0; t < nt; t++) {
    const int kb = TILE_KB(t);
    // prefetch next K tile
    bf16x8 kn0, kn1, kn2, kn3;
    const bool have_next = (t + 1 < nt);
    if (have_next) {
      const int nkb = TILE_KB(t + 1);
      LOADK(nkb, kn0, kn1, kn2, kn3)
    }
    // V fragments for this tile (independent -> issue early)
    bf16x8 vf0 = *(const bf16x8*)&Vh[(0 * 16 + fr) * S_LEN + kb + fk];
    bf16x8 vf1 = *(const bf16x8*)&Vh[(1 * 16 + fr) * S_LEN + kb + fk];
    bf16x8 vf2 = *(const bf16x8*)&Vh[(2 * 16 + fr) * S_LEN + kb + fk];
    bf16x8 vf3 = *(const bf16x8*)&Vh[(3 * 16 + fr) * S_LEN + kb + fk];

    f32x4 s0 = {0.f, 0.f, 0.f, 0.f}, s1 = {0.f, 0.f, 0.f, 0.f};
    s0 = __builtin_amdgcn_mfma_f32_16x16x32_bf16(kc0, aq0, s0, 0, 0, 0);
    s0 = __builtin_amdgcn_mfma_f32_16x16x32_bf16(kc1, aq1, s0, 0, 0, 0);
    s1 = __builtin_amdgcn_mfma_f32_16x16x32_bf16(kc2, aq0, s1, 0, 0, 0);
    s1 = __builtin_amdgcn_mfma_f32_16x16x32_bf16(kc3, aq1, s1, 0, 0, 0);

    // mask: i = iq (per-lane q), j = kb + cr + r (+16 for s1)
    float v[8];
#pragma unroll
    for (int r = 0; r < 4; r++) {
      const int j0 = kb + cr + r, j1 = j0 + 16;
      v[r] = (j0 <= iq && (iq - j0 <= WIN || j0 < NGLOB)) ? s0[r] : -1e30f;
      v[4 + r] = (j1 <= iq && (iq - j1 <= WIN || j1 < NGLOB)) ? s1[r] : -1e30f;
    }
    float mt = fmaxf(fmaxf(fmaxf(v[0], v[1]), fmaxf(v[2], v[3])),
                     fmaxf(fmaxf(v[4], v[5]), fmaxf(v[6], v[7])));
    mt = fmaxf(mt, __shfl_xor(mt, 16));
    mt = fmaxf(mt, __shfl_xor(mt, 32));
    const float mn = fmaxf(m_run, mt);
    const float alpha = __expf(m_run - mn);
    m_run = mn;
    float p[8];
    float ps = 0.f;
#pragma unroll
    for (int i = 0; i < 8; i++) {
      p[i] = __expf(v[i] - mn);
      ps += p[i];
    }
    ps += __shfl_xor(ps, 16);
    ps += __shfl_xor(ps, 32);
    l_run = l_run * alpha + ps;

    // pack P -> per-wave LDS: row q=fr, cols k = cr+{0..3}, 16+cr+{0..3}
    *(bf16x2*)&prow[cr] = bf16x2{(bf16_t)p[0], (bf16_t)p[1]};
    *(bf16x2*)&prow[cr + 2] = bf16x2{(bf16_t)p[2], (bf16_t)p[3]};
    *(bf16x2*)&prow[16 + cr] = bf16x2{(bf16_t)p[4], (bf16_t)p[5]};
    *(bf16x2*)&prow[16 + cr + 2] = bf16x2{(bf16_t)p[6], (bf16_t)p[7]};

    // alpha for PV-output rows q' = cr + r (held by lane q'=lane&15)
    float alpha_r[4];
#pragma unroll
    for (int r = 0; r < 4; r++) alpha_r[r] = __shfl(alpha, cr + r);

    // fence: keep the pa load after the same-iteration P stores
    asm volatile("" ::: "memory");
    const bf16x8 pa = *pread;  // P A-fragment: row=q'(=fr), k=fk..fk+7
    asm volatile("" ::: "memory");

#pragma unroll
    for (int fd = 0; fd < 4; fd++) {
#pragma unroll
      for (int r = 0; r < 4; r++) acc_o[fd][r] *= alpha_r[r];
    }
    acc_o[0] = __builtin_amdgcn_mfma_f32_16x16x32_bf16(pa, vf0, acc_o[0], 0, 0, 0);
    acc_o[1] = __builtin_amdgcn_mfma_f32_16x16x32_bf16(pa, vf1, acc_o[1], 0, 0, 0);
    acc_o[2] = __builtin_amdgcn_mfma_f32_16x16x32_bf16(pa, vf2, acc_o[2], 0, 0, 0);
    acc_o[3] = __builtin_amdgcn_mfma_f32_16x16x32_bf16(pa, vf3, acc_o[3], 0, 0, 0);

    if (have_next) {
      kc0 = kn0; kc1 = kn1; kc2 = kn2; kc3 = kn3;
    }
  }

  const float linv = 1.0f / l_run;  // for q = fr
  float inv_r[4];
#pragma unroll
  for (int r = 0; r < 4; r++) inv_r[r] = __shfl(linv, cr + r);

#pragma unroll
  for (int fd = 0; fd < 4; fd++)
#pragma unroll
    for (int r = 0; r < 4; r++) {
      const int s = q0 + cr + r;
      O[(size_t)s * D_MODEL + h * DKH + fd * 16 + fr] =
          (bf16_t)(acc_o[fd][r] * inv_r[r]);
    }
}

extern "C" void kernel_launch(void* const* d_in, const int* in_sizes, int n_in,
                              void* d_out, int out_size, void* d_ws,
                              size_t ws_size, hipStream_t stream) {
  const float* query = (const float*)d_in[0];
  const float* key = (const float*)d_in[1];
  const float* value = (const float*)d_in[2];
  const float* Wq = (const float*)d_in[3];
  const float* bq = (const float*)d_in[4];
  const float* Wk = (const float*)d_in[5];
  const float* bk = (const float*)d_in[6];
  const float* Wv = (const float*)d_in[7];
  const float* bv = (const float*)d_in[8];
  const float* Wo = (const float*)d_in[9];
  const float* bo = (const float*)d_in[10];

  char* ws = (char*)d_ws;
  bf16_t* Qb = (bf16_t*)(ws);                   // 8 MiB [16][4096][64]
  bf16_t* Kb = (bf16_t*)(ws + (8ull << 20));    // 8 MiB
  bf16_t* Vtb = (bf16_t*)(ws + (16ull << 20));  // 8 MiB [16][64][4096]
  bf16_t* Wt = (bf16_t*)(ws + (24ull << 20));   // 4 x 2 MiB (Wq^T..Wo^T)
  bf16_t* Xq = (bf16_t*)(ws + (32ull << 20));   // 8 MiB
  bf16_t* Xk = (bf16_t*)(ws + (40ull << 20));   // 8 MiB
  bf16_t* Xv = (bf16_t*)(ws + (48ull << 20));   // 8 MiB
  bf16_t* Ab = (bf16_t*)(ws + (56ull << 20));   // 8 MiB attn out [4096][1024]

  const size_t WSTRIDE = (size_t)D_MODEL * D_MODEL;

  convw<<<dim3(16, 16, 4), 256, 0, stream>>>(Wq, Wk, Wv, Wo, Wt);
  convx3<<<dim3(4096, 3), 256, 0, stream>>>(query, key, value, Xq, Xk, Xv);

  gemm_qkv<<<dim3(8, 32, 3), 256, 0, stream>>>(Xq, Xk, Xv, Wt, bq, bk, bv, Qb,
                                               Kb, Vtb);

  attn_kern<<<dim3(64, 16), 256, 0, stream>>>(Qb, Kb, Vtb, Ab);

  gemm_out<<<dim3(8, 32), 256, 0, stream>>>(Ab, Wt + 3 * WSTRIDE, bo,
                                            (float*)d_out);
}